// Round 18
// baseline (137.523 us; speedup 1.0000x reference)
//
#include <hip/hip_runtime.h>
#include <math.h>

// DynamicAttention1 — round 26: R23 anchor (127.2 best) + ONE change —
// stageD tiles widened 32x32 -> 32x64 (halve softmax redundancy).
// Ledger: R23=127.2 (cheap softmax win), R24 dbuf keys=129.1 REGRESS,
// R25 splitKx4 keys=133.2 REGRESS -> keys 400x16 splitKx2 is locally
// optimal; the only winning lever is cutting stageD serial work.
// wbuf depends only on (b,l0) but was computed 16x (once per n0-tile).
// Now grid (8 n-tiles of 64, 8 b, 4 l0) = 256 blocks: softmax ONCE per
// block, wP chunk-loop runs twice (n0, n0+32) reusing wbuf+Bs (leading
// syncthreads in chunk loop protects Bs between halves). Total softmax
// work halves; barriers/LDS unchanged. keys/qh/out_left/stageC = R23.
// Predict 127.2 -> ~123-125; null/regress -> stageD closed, attack prep
// or declare launch-structure floor.

typedef __attribute__((ext_vector_type(8))) short s16x8;
typedef __attribute__((ext_vector_type(4))) float f32x4;

__device__ __forceinline__ unsigned short f2bf(float f) {
    unsigned int u = __float_as_uint(f);
    return (unsigned short)((u + 0x7fffu + ((u >> 16) & 1u)) >> 16);  // RNE
}

__device__ __forceinline__ s16x8 cvt8(const float* p) {
    float4 u = *(const float4*)p, w = *(const float4*)(p + 4);
    s16x8 o;
    o[0] = (short)f2bf(u.x); o[1] = (short)f2bf(u.y);
    o[2] = (short)f2bf(u.z); o[3] = (short)f2bf(u.w);
    o[4] = (short)f2bf(w.x); o[5] = (short)f2bf(w.y);
    o[6] = (short)f2bf(w.z); o[7] = (short)f2bf(w.w);
    return o;
}

// ---------------- prep: weight transposes + keys zero-init ------------------
__global__ __launch_bounds__(256) void k_prep(
    const float* __restrict__ Wq, const float* __restrict__ Ws,
    const float* __restrict__ Wo,
    unsigned short* __restrict__ WqT, unsigned short* __restrict__ WsT,
    unsigned short* __restrict__ WoT, float* __restrict__ keys) {
    __shared__ float tile[32][33];
    const int bid = blockIdx.x, t = threadIdx.x;

    if (bid < 1792) {                       // weight transpose-cast, 32x32 tiles
        const int id = bid;
        const float* W; unsigned short* O; int K, tk, tn;
        if (id < 256)       { W = Wq; O = WqT; K = 512;  tk = id >> 4;          tn = id & 15; }
        else if (id < 1280) { W = Ws; O = WsT; K = 2048; tk = (id - 256) >> 4;  tn = (id - 256) & 15; }
        else                { W = Wo; O = WoT; K = 1024; tk = (id - 1280) >> 4; tn = (id - 1280) & 15; }
        const int row = t >> 3, c4 = (t & 7) * 4;
        float4 v = *(const float4*)(W + (size_t)(tk * 32 + row) * 512 + tn * 32 + c4);
        tile[row][c4 + 0] = v.x; tile[row][c4 + 1] = v.y;
        tile[row][c4 + 2] = v.z; tile[row][c4 + 3] = v.w;
        __syncthreads();
        ushort4 o = make_ushort4(f2bf(tile[c4 + 0][row]), f2bf(tile[c4 + 1][row]),
                                 f2bf(tile[c4 + 2][row]), f2bf(tile[c4 + 3][row]));
        *(ushort4*)(O + (size_t)(tn * 32 + row) * K + tk * 32 + c4) = o;
    } else {                                // keys = 0 (split-K base, unbiased)
        const int f = ((bid - 1792) * 256 + t) * 4;
        *(float4*)(keys + f) = make_float4(0.f, 0.f, 0.f, 0.f);
    }
}

// ---------------- keys GEMM: A = [src;trg] fp32 (cvt in staging) ------------
// 64x64 tile, 4 waves 2x2; split-K x2, atomics onto zeroed keys.
__device__ __forceinline__ void gemm64_keys(
    const float* __restrict__ src, const float* __restrict__ trg,
    const unsigned short* __restrict__ BT, float* __restrict__ C,
    int m0, int n0, int kbase, unsigned short* As, unsigned short* Bs) {
    const int t = threadIdx.x;
    const int lane = t & 63, wid = t >> 6;
    const int wm = (wid & 1) * 32, wn = (wid >> 1) * 32;
    const int lr = lane & 15, lq = lane >> 4;
    const int r = t >> 3, c8 = (t & 7) * 8;

    const int ra_row = m0 + r, rb_row = m0 + r + 32;
    const float* arp = (ra_row < 800) ? (src + (size_t)ra_row * 2048)
                                      : (trg + (size_t)(ra_row - 800) * 2048);
    const float* brp = (rb_row < 800) ? (src + (size_t)rb_row * 2048)
                                      : (trg + (size_t)(rb_row - 800) * 2048);

    s16x8 ra0, ra1, rb0, rb1;
#define LDK(kt)                                                            \
    ra0 = cvt8(arp + (kt) + c8);                                           \
    ra1 = cvt8(brp + (kt) + c8);                                           \
    rb0 = *(const s16x8*)(BT + (size_t)(n0 + r)      * 2048 + (kt) + c8);  \
    rb1 = *(const s16x8*)(BT + (size_t)(n0 + r + 32) * 2048 + (kt) + c8);

    f32x4 acc[2][2] = {};
    LDK(kbase);
    for (int it = 0; it < 16; it++) {
        __syncthreads();
        *(s16x8*)&As[r * 72 + c8]        = ra0;
        *(s16x8*)&As[(r + 32) * 72 + c8] = ra1;
        *(s16x8*)&Bs[r * 72 + c8]        = rb0;
        *(s16x8*)&Bs[(r + 32) * 72 + c8] = rb1;
        __syncthreads();
        if (it < 15) { LDK(kbase + (it + 1) * 64); }  // prefetch
#pragma unroll
        for (int s = 0; s < 2; s++) {
            s16x8 a0 = *(const s16x8*)&As[(wm + lr) * 72      + s * 32 + lq * 8];
            s16x8 a1 = *(const s16x8*)&As[(wm + 16 + lr) * 72 + s * 32 + lq * 8];
            s16x8 b0 = *(const s16x8*)&Bs[(wn + lr) * 72      + s * 32 + lq * 8];
            s16x8 b1 = *(const s16x8*)&Bs[(wn + 16 + lr) * 72 + s * 32 + lq * 8];
            acc[0][0] = __builtin_amdgcn_mfma_f32_16x16x32_bf16(a0, b0, acc[0][0], 0, 0, 0);
            acc[0][1] = __builtin_amdgcn_mfma_f32_16x16x32_bf16(a0, b1, acc[0][1], 0, 0, 0);
            acc[1][0] = __builtin_amdgcn_mfma_f32_16x16x32_bf16(a1, b0, acc[1][0], 0, 0, 0);
            acc[1][1] = __builtin_amdgcn_mfma_f32_16x16x32_bf16(a1, b1, acc[1][1], 0, 0, 0);
        }
    }
#undef LDK
#pragma unroll
    for (int i = 0; i < 2; i++)
#pragma unroll
        for (int j = 0; j < 2; j++) {
            const int col = n0 + wn + j * 16 + lr;      // C/D: col=lane&15
            const int row = m0 + wm + i * 16 + lq * 4;  //      row=quad*4+reg
#pragma unroll
            for (int rr = 0; rr < 4; rr++)
                unsafeAtomicAdd(&C[(size_t)(row + rr) * 512 + col], acc[i][j][rr]);
        }
}

// ---------------- P GEMM: P = keys @ WoBot (direct fp32 store) --------------
// 64x64 tile, 4 waves 2x2, K=512 (8 iters). A = keys fp32 cvt, B = wot+512.
__device__ __forceinline__ void gemm64_P(
    const float* __restrict__ keys, const unsigned short* __restrict__ wotBot,
    float* __restrict__ P, int m0, int n0, unsigned short* As,
    unsigned short* Bs) {
    const int t = threadIdx.x;
    const int lane = t & 63, wid = t >> 6;
    const int wm = (wid & 1) * 32, wn = (wid >> 1) * 32;
    const int lr = lane & 15, lq = lane >> 4;
    const int r = t >> 3, c8 = (t & 7) * 8;

    s16x8 ra0, ra1, rb0, rb1;
#define LDP(kt)                                                               \
    ra0 = cvt8(keys + (size_t)(m0 + r)      * 512 + (kt) + c8);               \
    ra1 = cvt8(keys + (size_t)(m0 + r + 32) * 512 + (kt) + c8);               \
    rb0 = *(const s16x8*)(wotBot + (size_t)(n0 + r)      * 1024 + (kt) + c8); \
    rb1 = *(const s16x8*)(wotBot + (size_t)(n0 + r + 32) * 1024 + (kt) + c8);

    f32x4 acc[2][2] = {};
    LDP(0);
    for (int it = 0; it < 8; it++) {
        __syncthreads();
        *(s16x8*)&As[r * 72 + c8]        = ra0;
        *(s16x8*)&As[(r + 32) * 72 + c8] = ra1;
        *(s16x8*)&Bs[r * 72 + c8]        = rb0;
        *(s16x8*)&Bs[(r + 32) * 72 + c8] = rb1;
        __syncthreads();
        if (it < 7) { LDP((it + 1) * 64); }  // prefetch
#pragma unroll
        for (int s = 0; s < 2; s++) {
            s16x8 a0 = *(const s16x8*)&As[(wm + lr) * 72      + s * 32 + lq * 8];
            s16x8 a1 = *(const s16x8*)&As[(wm + 16 + lr) * 72 + s * 32 + lq * 8];
            s16x8 b0 = *(const s16x8*)&Bs[(wn + lr) * 72      + s * 32 + lq * 8];
            s16x8 b1 = *(const s16x8*)&Bs[(wn + 16 + lr) * 72 + s * 32 + lq * 8];
            acc[0][0] = __builtin_amdgcn_mfma_f32_16x16x32_bf16(a0, b0, acc[0][0], 0, 0, 0);
            acc[0][1] = __builtin_amdgcn_mfma_f32_16x16x32_bf16(a0, b1, acc[0][1], 0, 0, 0);
            acc[1][0] = __builtin_amdgcn_mfma_f32_16x16x32_bf16(a1, b0, acc[1][0], 0, 0, 0);
            acc[1][1] = __builtin_amdgcn_mfma_f32_16x16x32_bf16(a1, b1, acc[1][1], 0, 0, 0);
        }
    }
#undef LDP
#pragma unroll
    for (int i = 0; i < 2; i++)
#pragma unroll
        for (int j = 0; j < 2; j++) {
            const int col = n0 + wn + j * 16 + lr;
            const int row = m0 + wm + i * 16 + lq * 4;
#pragma unroll
            for (int rr = 0; rr < 4; rr++)
                P[(size_t)(row + rr) * 512 + col] = acc[i][j][rr];
        }
}

// 32x64 tile, 4 waves. A fp32 (cvt in staging). MODE 0: fp32+bias,
// 2: bf16+bias.
template <int MODE>
__device__ __forceinline__ void gemm32(
    const float* __restrict__ A, const unsigned short* __restrict__ BT,
    const float* __restrict__ bias, void* __restrict__ Cv,
    int m0, int n0, int KA, int KB, int N, int kiters,
    unsigned short* As, unsigned short* Bs) {
    const int t = threadIdx.x;
    const int lane = t & 63, wid = t >> 6;
    const int wm = (wid & 1) * 16, wn = (wid >> 1) * 32;
    const int lr = lane & 15, lq = lane >> 4;
    const int r = t >> 3, c8 = (t & 7) * 8;

    s16x8 ra, rb0, rb1;
#define LD32(kt)                                                            \
    ra  = cvt8(A + (size_t)(m0 + r) * KA + (kt) + c8);                      \
    rb0 = *(const s16x8*)(BT + (size_t)(n0 + r)      * KB + (kt) + c8);     \
    rb1 = *(const s16x8*)(BT + (size_t)(n0 + r + 32) * KB + (kt) + c8);

    f32x4 acc[2] = {};
    LD32(0);
    for (int it = 0; it < kiters; it++) {
        __syncthreads();
        *(s16x8*)&As[r * 72 + c8]        = ra;
        *(s16x8*)&Bs[r * 72 + c8]        = rb0;
        *(s16x8*)&Bs[(r + 32) * 72 + c8] = rb1;
        __syncthreads();
        if (it + 1 < kiters) { LD32((it + 1) * 64); }  // prefetch
#pragma unroll
        for (int s = 0; s < 2; s++) {
            s16x8 a0 = *(const s16x8*)&As[(wm + lr) * 72      + s * 32 + lq * 8];
            s16x8 b0 = *(const s16x8*)&Bs[(wn + lr) * 72      + s * 32 + lq * 8];
            s16x8 b1 = *(const s16x8*)&Bs[(wn + 16 + lr) * 72 + s * 32 + lq * 8];
            acc[0] = __builtin_amdgcn_mfma_f32_16x16x32_bf16(a0, b0, acc[0], 0, 0, 0);
            acc[1] = __builtin_amdgcn_mfma_f32_16x16x32_bf16(a0, b1, acc[1], 0, 0, 0);
        }
    }
#undef LD32
#pragma unroll
    for (int j = 0; j < 2; j++) {
        const int col = n0 + wn + j * 16 + lr;
        const int row = m0 + wm + lq * 4;
        const float bv = bias[col];
        if (MODE == 0) {
            float* C = (float*)Cv;
#pragma unroll
            for (int rr = 0; rr < 4; rr++)
                C[(size_t)(row + rr) * N + col] = acc[j][rr] + bv;
        } else {
            unsigned short* C = (unsigned short*)Cv;
#pragma unroll
            for (int rr = 0; rr < 4; rr++)
                C[(size_t)(row + rr) * N + col] = f2bf(acc[j][rr] + bv);
        }
    }
}

// ---------------- stage B: keys splitKx2 + qh + out_left --------------------
__global__ __launch_bounds__(256) void k_stageB(
    const float* __restrict__ query, const float* __restrict__ src,
    const float* __restrict__ trg, const unsigned short* __restrict__ WqT,
    const unsigned short* __restrict__ WsT, const unsigned short* __restrict__ WoT,
    const float* __restrict__ bq, const float* __restrict__ bo,
    unsigned short* __restrict__ qh, float* __restrict__ keys,
    float* __restrict__ out) {
    __shared__ __align__(16) unsigned short As[64 * 72];
    __shared__ __align__(16) unsigned short Bs[64 * 72];
    const int bid = blockIdx.x;
    if (bid < 400) {
        const int c = bid / 200, rem = bid % 200;
        const int mt = rem >> 3, nt = rem & 7;
        gemm64_keys(src, trg, WsT, keys, mt * 64, nt * 64, c * 1024, As, Bs);
    } else if (bid < 656) {
        const int r = bid - 400;
        const int mt = r >> 3, nt = r & 7;
        gemm32<2>(query, WqT, bq, qh, mt * 32, nt * 64, 512, 512, 512,
                  8, As, Bs);
    } else {
        const int r = bid - 656;
        const int mt = r >> 3, nt = r & 7;
        gemm32<0>(query, WoT, bo, out, mt * 32, nt * 64, 512, 1024, 512,
                  8, As, Bs);
    }
}

// ---------------- stage C: scgemm (128 blocks) + Pgemm (200 blocks) ---------
// scgemm: sc[b*128+l][n], cols 0..99 = qs/32, cols 128..227 = -qt/32.
// Pgemm:  P = keys @ WoBot, [1600][512] fp32 direct.
__global__ __launch_bounds__(256) void k_stageC(
    const unsigned short* __restrict__ qh, const float* __restrict__ keys,
    const unsigned short* __restrict__ wotBot, float* __restrict__ sc,
    float* __restrict__ P) {
    __shared__ __align__(16) unsigned short As[64 * 72];
    __shared__ __align__(16) unsigned short Bs[64 * 72];
    const int bid = blockIdx.x;
    const int t = threadIdx.x;

    if (bid >= 128) {                       // ---- Pgemm ----
        const int rem = bid - 128;
        gemm64_P(keys, wotBot, P, (rem >> 3) * 64, (rem & 7) * 64, As, Bs);
        return;
    }

    // ---- scgemm ----
    const int mt = bid >> 2, nt = bid & 3;
    const int m0 = mt * 32, b = mt >> 2, n0 = nt * 64;
    const int lane = t & 63, wid = t >> 6;
    const int wm = (wid & 1) * 16, wn = (wid >> 1) * 32;
    const int lr = lane & 15, lq = lane >> 4;
    const int r = t >> 3, c8 = (t & 7) * 8;

    const int nA = n0 + r, nB = n0 + r + 32;
    int kr0 = (nA < 128) ? (b * 100 + nA) : (800 + b * 100 + (nA - 128));
    int kr1 = (nB < 128) ? (b * 100 + nB) : (800 + b * 100 + (nB - 128));
    kr0 = kr0 > 1599 ? 1599 : kr0;
    kr1 = kr1 > 1599 ? 1599 : kr1;

    s16x8 ra, rb0, rb1;
#define LDSC(kt)                                                    \
    ra  = *(const s16x8*)(qh + (size_t)(m0 + r) * 512 + (kt) + c8); \
    rb0 = cvt8(keys + (size_t)kr0 * 512 + (kt) + c8);               \
    rb1 = cvt8(keys + (size_t)kr1 * 512 + (kt) + c8);

    f32x4 acc[2] = {};
    LDSC(0);
    for (int it = 0; it < 8; it++) {
        __syncthreads();
        *(s16x8*)&As[r * 72 + c8]        = ra;
        *(s16x8*)&Bs[r * 72 + c8]        = rb0;
        *(s16x8*)&Bs[(r + 32) * 72 + c8] = rb1;
        __syncthreads();
        if (it < 7) { LDSC((it + 1) * 64); }
#pragma unroll
        for (int s = 0; s < 2; s++) {
            s16x8 a0 = *(const s16x8*)&As[(wm + lr) * 72      + s * 32 + lq * 8];
            s16x8 b0 = *(const s16x8*)&Bs[(wn + lr) * 72      + s * 32 + lq * 8];
            s16x8 b1 = *(const s16x8*)&Bs[(wn + 16 + lr) * 72 + s * 32 + lq * 8];
            acc[0] = __builtin_amdgcn_mfma_f32_16x16x32_bf16(a0, b0, acc[0], 0, 0, 0);
            acc[1] = __builtin_amdgcn_mfma_f32_16x16x32_bf16(a0, b1, acc[1], 0, 0, 0);
        }
    }
#undef LDSC
#pragma unroll
    for (int j = 0; j < 2; j++) {
        const int col = n0 + wn + j * 16 + lr;
        const int row = m0 + wm + lq * 4;
        const float scale = (col >= 128) ? -(1.0f / 32.0f) : (1.0f / 32.0f);
#pragma unroll
        for (int rr = 0; rr < 4; rr++)
            sc[(size_t)(row + rr) * 256 + col] = acc[j][rr] * scale;
    }
}

// ---------------- stage D: cheap softmax (1x per 64 cols) + wP GEMM ---------
// grid (8 n-tiles of 64, 8 b, 4 l-tiles) = 256 blocks of 32(l) x 64(n).
// Softmax ONCE per block; wP chunk-loop runs twice (n0, n0+32) reusing
// wbuf and Bs (leading syncthreads protects Bs between halves).
__global__ __launch_bounds__(256) void k_stageD(
    const float* __restrict__ sc, const float* __restrict__ P,
    float* __restrict__ out) {
    __shared__ float wbuf[200 * 33];     // [st][l], pad 33
    __shared__ float Bs[40 * 32];        // [k][n]

    const int t = threadIdx.x;
    const int b = blockIdx.y;
    const int n0 = blockIdx.x * 64;
    const int l0 = blockIdx.z * 32;
    const int wave = t >> 6, lane = t & 63;

    // ---- softmax (no-max, half-reduce) — ONCE per block ----
    for (int i = 0; i < 8; i++) {
        const int li = wave * 8 + i;                  // 0..31
        const float4 v = *(const float4*)(
            sc + (size_t)(b * 128 + l0 + li) * 256 + lane * 4);
        const float vv[4] = {v.x, v.y, v.z, v.w};
        const int c0 = lane * 4;
        float e[4], s = 0.f;
#pragma unroll
        for (int j = 0; j < 4; j++) {
            const int col = c0 + j;
            const bool valid = (col < 100) | (col >= 128 && col < 228);
            e[j] = valid ? __expf(vv[j]) : 0.f;
            s += e[j];
        }
#pragma unroll
        for (int off = 16; off > 0; off >>= 1) s += __shfl_xor(s, off);
        const float inv = 1.f / s;                    // lanes<32: 1/sS; >=32: 1/sT
#pragma unroll
        for (int j = 0; j < 4; j++) {
            const int col = c0 + j;
            if (col < 100) wbuf[col * 33 + li] = e[j] * inv;
            else if (col >= 128 && col < 228)
                wbuf[(100 + col - 128) * 33 + li] = e[j] * inv;
        }
    }

    // ---- GEMM twice: acc[l][n] += w[st][l] * (+P_s|-P_t)[st][n] ------------
    const int tx = t & 7, ty = t >> 3;   // tx: n/4, ty: l
    const float s2 = 0.70710678118654752f;  // 1/sqrt(2)
    const int m = b * 128 + l0 + ty;

    for (int half = 0; half < 2; half++) {
        const int nh = n0 + half * 32;
        float rB[5];
        auto loadB = [&](int kbase) {
#pragma unroll
            for (int e2 = 0; e2 < 5; e2++) {
                const int idx = t + e2 * 256;
                const int k = idx >> 5, j = idx & 31;
                const int kk = kbase + k;
                rB[e2] = (kk < 100)
                    ?  P[(size_t)(b * 100 + kk) * 512 + nh + j]
                    : -P[(size_t)(800 + b * 100 + (kk - 100)) * 512 + nh + j];
            }
        };

        float acc[4] = {};
        loadB(0);
        for (int c5 = 0; c5 < 5; c5++) {
            __syncthreads();
#pragma unroll
            for (int e2 = 0; e2 < 5; e2++) {
                const int idx = t + e2 * 256;
                Bs[idx] = rB[e2];
            }
            __syncthreads();
            if (c5 < 4) loadB((c5 + 1) * 40);          // prefetch next chunk
#pragma unroll 8
            for (int k = 0; k < 40; k++) {
                const float ar = wbuf[(c5 * 40 + k) * 33 + ty];
                float br[4];
                *(float4*)br = *(const float4*)&Bs[k * 32 + tx * 4];
#pragma unroll
                for (int j = 0; j < 4; j++) acc[j] = fmaf(ar, br[j], acc[j]);
            }
        }

#pragma unroll
        for (int j = 0; j < 4; j++)
            unsafeAtomicAdd(&out[(size_t)m * 512 + nh + tx * 4 + j],
                            acc[j] * s2);
    }
}

// ---------------- launch ----------------------------------------------------

extern "C" void kernel_launch(void* const* d_in, const int* in_sizes, int n_in,
                              void* d_out, int out_size, void* d_ws, size_t ws_size,
                              hipStream_t stream) {
    const float* query = (const float*)d_in[0];
    const float* src   = (const float*)d_in[1];
    const float* trg   = (const float*)d_in[2];
    const float* Wq    = (const float*)d_in[3];
    const float* bq    = (const float*)d_in[4];
    const float* Ws    = (const float*)d_in[5];
    const float* Wo    = (const float*)d_in[7];
    const float* bo    = (const float*)d_in[8];
    float* out = (float*)d_out;

    float* keys = (float*)d_ws;               // 1600*512 fp32 (UNBIASED)
    float* sc   = keys + 819200;              // 1024*256 fp32
    float* P    = sc   + 262144;              // 1600*512 fp32 = keys @ WoBot
    unsigned short* qh  = (unsigned short*)(P + 819200);  // 1024x512 bf16
    unsigned short* wqt = qh  + 524288;       // WqT 512x512
    unsigned short* wst = wqt + 262144;       // WsT 512x2048
    unsigned short* wot = wst + 1048576;      // WoT 512x1024

    k_prep<<<2592, 256, 0, stream>>>(Wq, Ws, Wo, wqt, wst, wot, keys);
    k_stageB<<<912, 256, 0, stream>>>(query, src, trg, wqt, wst, wot, bq, bo,
                                      qh, keys, out);
    k_stageC<<<328, 256, 0, stream>>>(qh, keys, wot + 512, sc, P);
    k_stageD<<<dim3(8, 8, 4), 256, 0, stream>>>(sc, P, out);
}

// Round 19
// 128.607 us; speedup vs baseline: 1.0693x; 1.0693x over previous
//
#include <hip/hip_runtime.h>
#include <math.h>

// DynamicAttention1 — round 27: RESTORE R23 (127.2us session best).
// R26 (stageD 32x64) regressed to 137.5 — occupancy cliff (512->256 blocks)
// swamped the halved softmax. Ledger around R23: dbuf keys 129.1, splitKx4
// 133.2, wide stageD 137.5 — ALL single-variable probes regress; R23 is a
// genuine local optimum. Pipeline is launch-structure-bound: ~11us MFMA +
// ~17us traffic + ~100us dependent-launch latency & low-occupancy tails;
// coop fusion measured WORSE (grid.sync ~57us/fence on 8 XCDs). Restoring
// the champion: R12 anchor structure + cheap no-max half-reduce softmax.

typedef __attribute__((ext_vector_type(8))) short s16x8;
typedef __attribute__((ext_vector_type(4))) float f32x4;

__device__ __forceinline__ unsigned short f2bf(float f) {
    unsigned int u = __float_as_uint(f);
    return (unsigned short)((u + 0x7fffu + ((u >> 16) & 1u)) >> 16);  // RNE
}

__device__ __forceinline__ s16x8 cvt8(const float* p) {
    float4 u = *(const float4*)p, w = *(const float4*)(p + 4);
    s16x8 o;
    o[0] = (short)f2bf(u.x); o[1] = (short)f2bf(u.y);
    o[2] = (short)f2bf(u.z); o[3] = (short)f2bf(u.w);
    o[4] = (short)f2bf(w.x); o[5] = (short)f2bf(w.y);
    o[6] = (short)f2bf(w.z); o[7] = (short)f2bf(w.w);
    return o;
}

// ---------------- prep: weight transposes + keys zero-init ------------------
__global__ __launch_bounds__(256) void k_prep(
    const float* __restrict__ Wq, const float* __restrict__ Ws,
    const float* __restrict__ Wo,
    unsigned short* __restrict__ WqT, unsigned short* __restrict__ WsT,
    unsigned short* __restrict__ WoT, float* __restrict__ keys) {
    __shared__ float tile[32][33];
    const int bid = blockIdx.x, t = threadIdx.x;

    if (bid < 1792) {                       // weight transpose-cast, 32x32 tiles
        const int id = bid;
        const float* W; unsigned short* O; int K, tk, tn;
        if (id < 256)       { W = Wq; O = WqT; K = 512;  tk = id >> 4;          tn = id & 15; }
        else if (id < 1280) { W = Ws; O = WsT; K = 2048; tk = (id - 256) >> 4;  tn = (id - 256) & 15; }
        else                { W = Wo; O = WoT; K = 1024; tk = (id - 1280) >> 4; tn = (id - 1280) & 15; }
        const int row = t >> 3, c4 = (t & 7) * 4;
        float4 v = *(const float4*)(W + (size_t)(tk * 32 + row) * 512 + tn * 32 + c4);
        tile[row][c4 + 0] = v.x; tile[row][c4 + 1] = v.y;
        tile[row][c4 + 2] = v.z; tile[row][c4 + 3] = v.w;
        __syncthreads();
        ushort4 o = make_ushort4(f2bf(tile[c4 + 0][row]), f2bf(tile[c4 + 1][row]),
                                 f2bf(tile[c4 + 2][row]), f2bf(tile[c4 + 3][row]));
        *(ushort4*)(O + (size_t)(tn * 32 + row) * K + tk * 32 + c4) = o;
    } else {                                // keys = 0 (split-K base, unbiased)
        const int f = ((bid - 1792) * 256 + t) * 4;
        *(float4*)(keys + f) = make_float4(0.f, 0.f, 0.f, 0.f);
    }
}

// ---------------- keys GEMM: A = [src;trg] fp32 (cvt in staging) ------------
// 64x64 tile, 4 waves 2x2; split-K x2, atomics onto zeroed keys.
__device__ __forceinline__ void gemm64_keys(
    const float* __restrict__ src, const float* __restrict__ trg,
    const unsigned short* __restrict__ BT, float* __restrict__ C,
    int m0, int n0, int kbase, unsigned short* As, unsigned short* Bs) {
    const int t = threadIdx.x;
    const int lane = t & 63, wid = t >> 6;
    const int wm = (wid & 1) * 32, wn = (wid >> 1) * 32;
    const int lr = lane & 15, lq = lane >> 4;
    const int r = t >> 3, c8 = (t & 7) * 8;

    const int ra_row = m0 + r, rb_row = m0 + r + 32;
    const float* arp = (ra_row < 800) ? (src + (size_t)ra_row * 2048)
                                      : (trg + (size_t)(ra_row - 800) * 2048);
    const float* brp = (rb_row < 800) ? (src + (size_t)rb_row * 2048)
                                      : (trg + (size_t)(rb_row - 800) * 2048);

    s16x8 ra0, ra1, rb0, rb1;
#define LDK(kt)                                                            \
    ra0 = cvt8(arp + (kt) + c8);                                           \
    ra1 = cvt8(brp + (kt) + c8);                                           \
    rb0 = *(const s16x8*)(BT + (size_t)(n0 + r)      * 2048 + (kt) + c8);  \
    rb1 = *(const s16x8*)(BT + (size_t)(n0 + r + 32) * 2048 + (kt) + c8);

    f32x4 acc[2][2] = {};
    LDK(kbase);
    for (int it = 0; it < 16; it++) {
        __syncthreads();
        *(s16x8*)&As[r * 72 + c8]        = ra0;
        *(s16x8*)&As[(r + 32) * 72 + c8] = ra1;
        *(s16x8*)&Bs[r * 72 + c8]        = rb0;
        *(s16x8*)&Bs[(r + 32) * 72 + c8] = rb1;
        __syncthreads();
        if (it < 15) { LDK(kbase + (it + 1) * 64); }  // prefetch
#pragma unroll
        for (int s = 0; s < 2; s++) {
            s16x8 a0 = *(const s16x8*)&As[(wm + lr) * 72      + s * 32 + lq * 8];
            s16x8 a1 = *(const s16x8*)&As[(wm + 16 + lr) * 72 + s * 32 + lq * 8];
            s16x8 b0 = *(const s16x8*)&Bs[(wn + lr) * 72      + s * 32 + lq * 8];
            s16x8 b1 = *(const s16x8*)&Bs[(wn + 16 + lr) * 72 + s * 32 + lq * 8];
            acc[0][0] = __builtin_amdgcn_mfma_f32_16x16x32_bf16(a0, b0, acc[0][0], 0, 0, 0);
            acc[0][1] = __builtin_amdgcn_mfma_f32_16x16x32_bf16(a0, b1, acc[0][1], 0, 0, 0);
            acc[1][0] = __builtin_amdgcn_mfma_f32_16x16x32_bf16(a1, b0, acc[1][0], 0, 0, 0);
            acc[1][1] = __builtin_amdgcn_mfma_f32_16x16x32_bf16(a1, b1, acc[1][1], 0, 0, 0);
        }
    }
#undef LDK
#pragma unroll
    for (int i = 0; i < 2; i++)
#pragma unroll
        for (int j = 0; j < 2; j++) {
            const int col = n0 + wn + j * 16 + lr;      // C/D: col=lane&15
            const int row = m0 + wm + i * 16 + lq * 4;  //      row=quad*4+reg
#pragma unroll
            for (int rr = 0; rr < 4; rr++)
                unsafeAtomicAdd(&C[(size_t)(row + rr) * 512 + col], acc[i][j][rr]);
        }
}

// ---------------- P GEMM: P = keys @ WoBot (direct fp32 store) --------------
// 64x64 tile, 4 waves 2x2, K=512 (8 iters). A = keys fp32 cvt, B = wot+512.
__device__ __forceinline__ void gemm64_P(
    const float* __restrict__ keys, const unsigned short* __restrict__ wotBot,
    float* __restrict__ P, int m0, int n0, unsigned short* As,
    unsigned short* Bs) {
    const int t = threadIdx.x;
    const int lane = t & 63, wid = t >> 6;
    const int wm = (wid & 1) * 32, wn = (wid >> 1) * 32;
    const int lr = lane & 15, lq = lane >> 4;
    const int r = t >> 3, c8 = (t & 7) * 8;

    s16x8 ra0, ra1, rb0, rb1;
#define LDP(kt)                                                               \
    ra0 = cvt8(keys + (size_t)(m0 + r)      * 512 + (kt) + c8);               \
    ra1 = cvt8(keys + (size_t)(m0 + r + 32) * 512 + (kt) + c8);               \
    rb0 = *(const s16x8*)(wotBot + (size_t)(n0 + r)      * 1024 + (kt) + c8); \
    rb1 = *(const s16x8*)(wotBot + (size_t)(n0 + r + 32) * 1024 + (kt) + c8);

    f32x4 acc[2][2] = {};
    LDP(0);
    for (int it = 0; it < 8; it++) {
        __syncthreads();
        *(s16x8*)&As[r * 72 + c8]        = ra0;
        *(s16x8*)&As[(r + 32) * 72 + c8] = ra1;
        *(s16x8*)&Bs[r * 72 + c8]        = rb0;
        *(s16x8*)&Bs[(r + 32) * 72 + c8] = rb1;
        __syncthreads();
        if (it < 7) { LDP((it + 1) * 64); }  // prefetch
#pragma unroll
        for (int s = 0; s < 2; s++) {
            s16x8 a0 = *(const s16x8*)&As[(wm + lr) * 72      + s * 32 + lq * 8];
            s16x8 a1 = *(const s16x8*)&As[(wm + 16 + lr) * 72 + s * 32 + lq * 8];
            s16x8 b0 = *(const s16x8*)&Bs[(wn + lr) * 72      + s * 32 + lq * 8];
            s16x8 b1 = *(const s16x8*)&Bs[(wn + 16 + lr) * 72 + s * 32 + lq * 8];
            acc[0][0] = __builtin_amdgcn_mfma_f32_16x16x32_bf16(a0, b0, acc[0][0], 0, 0, 0);
            acc[0][1] = __builtin_amdgcn_mfma_f32_16x16x32_bf16(a0, b1, acc[0][1], 0, 0, 0);
            acc[1][0] = __builtin_amdgcn_mfma_f32_16x16x32_bf16(a1, b0, acc[1][0], 0, 0, 0);
            acc[1][1] = __builtin_amdgcn_mfma_f32_16x16x32_bf16(a1, b1, acc[1][1], 0, 0, 0);
        }
    }
#undef LDP
#pragma unroll
    for (int i = 0; i < 2; i++)
#pragma unroll
        for (int j = 0; j < 2; j++) {
            const int col = n0 + wn + j * 16 + lr;
            const int row = m0 + wm + i * 16 + lq * 4;
#pragma unroll
            for (int rr = 0; rr < 4; rr++)
                P[(size_t)(row + rr) * 512 + col] = acc[i][j][rr];
        }
}

// 32x64 tile, 4 waves. A fp32 (cvt in staging). MODE 0: fp32+bias,
// 2: bf16+bias.
template <int MODE>
__device__ __forceinline__ void gemm32(
    const float* __restrict__ A, const unsigned short* __restrict__ BT,
    const float* __restrict__ bias, void* __restrict__ Cv,
    int m0, int n0, int KA, int KB, int N, int kiters,
    unsigned short* As, unsigned short* Bs) {
    const int t = threadIdx.x;
    const int lane = t & 63, wid = t >> 6;
    const int wm = (wid & 1) * 16, wn = (wid >> 1) * 32;
    const int lr = lane & 15, lq = lane >> 4;
    const int r = t >> 3, c8 = (t & 7) * 8;

    s16x8 ra, rb0, rb1;
#define LD32(kt)                                                            \
    ra  = cvt8(A + (size_t)(m0 + r) * KA + (kt) + c8);                      \
    rb0 = *(const s16x8*)(BT + (size_t)(n0 + r)      * KB + (kt) + c8);     \
    rb1 = *(const s16x8*)(BT + (size_t)(n0 + r + 32) * KB + (kt) + c8);

    f32x4 acc[2] = {};
    LD32(0);
    for (int it = 0; it < kiters; it++) {
        __syncthreads();
        *(s16x8*)&As[r * 72 + c8]        = ra;
        *(s16x8*)&Bs[r * 72 + c8]        = rb0;
        *(s16x8*)&Bs[(r + 32) * 72 + c8] = rb1;
        __syncthreads();
        if (it + 1 < kiters) { LD32((it + 1) * 64); }  // prefetch
#pragma unroll
        for (int s = 0; s < 2; s++) {
            s16x8 a0 = *(const s16x8*)&As[(wm + lr) * 72      + s * 32 + lq * 8];
            s16x8 b0 = *(const s16x8*)&Bs[(wn + lr) * 72      + s * 32 + lq * 8];
            s16x8 b1 = *(const s16x8*)&Bs[(wn + 16 + lr) * 72 + s * 32 + lq * 8];
            acc[0] = __builtin_amdgcn_mfma_f32_16x16x32_bf16(a0, b0, acc[0], 0, 0, 0);
            acc[1] = __builtin_amdgcn_mfma_f32_16x16x32_bf16(a0, b1, acc[1], 0, 0, 0);
        }
    }
#undef LD32
#pragma unroll
    for (int j = 0; j < 2; j++) {
        const int col = n0 + wn + j * 16 + lr;
        const int row = m0 + wm + lq * 4;
        const float bv = bias[col];
        if (MODE == 0) {
            float* C = (float*)Cv;
#pragma unroll
            for (int rr = 0; rr < 4; rr++)
                C[(size_t)(row + rr) * N + col] = acc[j][rr] + bv;
        } else {
            unsigned short* C = (unsigned short*)Cv;
#pragma unroll
            for (int rr = 0; rr < 4; rr++)
                C[(size_t)(row + rr) * N + col] = f2bf(acc[j][rr] + bv);
        }
    }
}

// ---------------- stage B: keys splitKx2 + qh + out_left --------------------
__global__ __launch_bounds__(256) void k_stageB(
    const float* __restrict__ query, const float* __restrict__ src,
    const float* __restrict__ trg, const unsigned short* __restrict__ WqT,
    const unsigned short* __restrict__ WsT, const unsigned short* __restrict__ WoT,
    const float* __restrict__ bq, const float* __restrict__ bo,
    unsigned short* __restrict__ qh, float* __restrict__ keys,
    float* __restrict__ out) {
    __shared__ __align__(16) unsigned short As[64 * 72];
    __shared__ __align__(16) unsigned short Bs[64 * 72];
    const int bid = blockIdx.x;
    if (bid < 400) {
        const int c = bid / 200, rem = bid % 200;
        const int mt = rem >> 3, nt = rem & 7;
        gemm64_keys(src, trg, WsT, keys, mt * 64, nt * 64, c * 1024, As, Bs);
    } else if (bid < 656) {
        const int r = bid - 400;
        const int mt = r >> 3, nt = r & 7;
        gemm32<2>(query, WqT, bq, qh, mt * 32, nt * 64, 512, 512, 512,
                  8, As, Bs);
    } else {
        const int r = bid - 656;
        const int mt = r >> 3, nt = r & 7;
        gemm32<0>(query, WoT, bo, out, mt * 32, nt * 64, 512, 1024, 512,
                  8, As, Bs);
    }
}

// ---------------- stage C: scgemm (128 blocks) + Pgemm (200 blocks) ---------
// scgemm: sc[b*128+l][n], cols 0..99 = qs/32, cols 128..227 = -qt/32.
// Pgemm:  P = keys @ WoBot, [1600][512] fp32 direct.
__global__ __launch_bounds__(256) void k_stageC(
    const unsigned short* __restrict__ qh, const float* __restrict__ keys,
    const unsigned short* __restrict__ wotBot, float* __restrict__ sc,
    float* __restrict__ P) {
    __shared__ __align__(16) unsigned short As[64 * 72];
    __shared__ __align__(16) unsigned short Bs[64 * 72];
    const int bid = blockIdx.x;
    const int t = threadIdx.x;

    if (bid >= 128) {                       // ---- Pgemm ----
        const int rem = bid - 128;
        gemm64_P(keys, wotBot, P, (rem >> 3) * 64, (rem & 7) * 64, As, Bs);
        return;
    }

    // ---- scgemm ----
    const int mt = bid >> 2, nt = bid & 3;
    const int m0 = mt * 32, b = mt >> 2, n0 = nt * 64;
    const int lane = t & 63, wid = t >> 6;
    const int wm = (wid & 1) * 16, wn = (wid >> 1) * 32;
    const int lr = lane & 15, lq = lane >> 4;
    const int r = t >> 3, c8 = (t & 7) * 8;

    const int nA = n0 + r, nB = n0 + r + 32;
    int kr0 = (nA < 128) ? (b * 100 + nA) : (800 + b * 100 + (nA - 128));
    int kr1 = (nB < 128) ? (b * 100 + nB) : (800 + b * 100 + (nB - 128));
    kr0 = kr0 > 1599 ? 1599 : kr0;
    kr1 = kr1 > 1599 ? 1599 : kr1;

    s16x8 ra, rb0, rb1;
#define LDSC(kt)                                                    \
    ra  = *(const s16x8*)(qh + (size_t)(m0 + r) * 512 + (kt) + c8); \
    rb0 = cvt8(keys + (size_t)kr0 * 512 + (kt) + c8);               \
    rb1 = cvt8(keys + (size_t)kr1 * 512 + (kt) + c8);

    f32x4 acc[2] = {};
    LDSC(0);
    for (int it = 0; it < 8; it++) {
        __syncthreads();
        *(s16x8*)&As[r * 72 + c8]        = ra;
        *(s16x8*)&Bs[r * 72 + c8]        = rb0;
        *(s16x8*)&Bs[(r + 32) * 72 + c8] = rb1;
        __syncthreads();
        if (it < 7) { LDSC((it + 1) * 64); }
#pragma unroll
        for (int s = 0; s < 2; s++) {
            s16x8 a0 = *(const s16x8*)&As[(wm + lr) * 72      + s * 32 + lq * 8];
            s16x8 b0 = *(const s16x8*)&Bs[(wn + lr) * 72      + s * 32 + lq * 8];
            s16x8 b1 = *(const s16x8*)&Bs[(wn + 16 + lr) * 72 + s * 32 + lq * 8];
            acc[0] = __builtin_amdgcn_mfma_f32_16x16x32_bf16(a0, b0, acc[0], 0, 0, 0);
            acc[1] = __builtin_amdgcn_mfma_f32_16x16x32_bf16(a0, b1, acc[1], 0, 0, 0);
        }
    }
#undef LDSC
#pragma unroll
    for (int j = 0; j < 2; j++) {
        const int col = n0 + wn + j * 16 + lr;
        const int row = m0 + wm + lq * 4;
        const float scale = (col >= 128) ? -(1.0f / 32.0f) : (1.0f / 32.0f);
#pragma unroll
        for (int rr = 0; rr < 4; rr++)
            sc[(size_t)(row + rr) * 256 + col] = acc[j][rr] * scale;
    }
}

// ---------------- stage D: cheap softmax + wP GEMM -> atomic into out -------
// grid (16 n-tiles, 8 b, 4 l-tiles) = 512 blocks of 32(l) x 32(n), K=200.
// Softmax WITHOUT max-subtraction (|score|<~8 -> fp32 exp safe); S-cols in
// lanes 0..31, T-cols in 32..63 -> one 5-step shfl_xor reduces each half.
__global__ __launch_bounds__(256) void k_stageD(
    const float* __restrict__ sc, const float* __restrict__ P,
    float* __restrict__ out) {
    __shared__ float wbuf[200 * 33];     // [st][l], pad 33
    __shared__ float Bs[40 * 32];        // [k][n]

    const int t = threadIdx.x;
    const int b = blockIdx.y;
    const int n0 = blockIdx.x * 32;
    const int l0 = blockIdx.z * 32;
    const int wave = t >> 6, lane = t & 63;

    // ---- softmax (no-max, half-reduce) ----
    for (int i = 0; i < 8; i++) {
        const int li = wave * 8 + i;                  // 0..31
        const float4 v = *(const float4*)(
            sc + (size_t)(b * 128 + l0 + li) * 256 + lane * 4);
        const float vv[4] = {v.x, v.y, v.z, v.w};
        const int c0 = lane * 4;
        float e[4], s = 0.f;
#pragma unroll
        for (int j = 0; j < 4; j++) {
            const int col = c0 + j;
            const bool valid = (col < 100) | (col >= 128 && col < 228);
            e[j] = valid ? __expf(vv[j]) : 0.f;
            s += e[j];
        }
#pragma unroll
        for (int off = 16; off > 0; off >>= 1) s += __shfl_xor(s, off);
        const float inv = 1.f / s;                    // lanes<32: 1/sS; >=32: 1/sT
#pragma unroll
        for (int j = 0; j < 4; j++) {
            const int col = c0 + j;
            if (col < 100) wbuf[col * 33 + li] = e[j] * inv;
            else if (col >= 128 && col < 228)
                wbuf[(100 + col - 128) * 33 + li] = e[j] * inv;
        }
    }
    __syncthreads();

    // ---- GEMM: acc[l][n] += w[st][l] * (+P_s|-P_t)[st][n] ------------------
    const int tx = t & 7, ty = t >> 3;   // tx: n/4, ty: l
    float rB[5];
    auto loadB = [&](int kbase) {
#pragma unroll
        for (int e2 = 0; e2 < 5; e2++) {
            const int idx = t + e2 * 256;
            const int k = idx >> 5, j = idx & 31;
            const int kk = kbase + k;
            rB[e2] = (kk < 100)
                ?  P[(size_t)(b * 100 + kk) * 512 + n0 + j]
                : -P[(size_t)(800 + b * 100 + (kk - 100)) * 512 + n0 + j];
        }
    };

    float acc[4] = {};
    loadB(0);
    for (int c5 = 0; c5 < 5; c5++) {
        __syncthreads();
#pragma unroll
        for (int e2 = 0; e2 < 5; e2++) {
            const int idx = t + e2 * 256;
            Bs[idx] = rB[e2];
        }
        __syncthreads();
        if (c5 < 4) loadB((c5 + 1) * 40);          // prefetch next chunk
#pragma unroll 8
        for (int k = 0; k < 40; k++) {
            const float ar = wbuf[(c5 * 40 + k) * 33 + ty];
            float br[4];
            *(float4*)br = *(const float4*)&Bs[k * 32 + tx * 4];
#pragma unroll
            for (int j = 0; j < 4; j++) acc[j] = fmaf(ar, br[j], acc[j]);
        }
    }

    const float s2 = 0.70710678118654752f;  // 1/sqrt(2)
    const int m = b * 128 + l0 + ty;
#pragma unroll
    for (int j = 0; j < 4; j++)
        unsafeAtomicAdd(&out[(size_t)m * 512 + n0 + tx * 4 + j], acc[j] * s2);
}

// ---------------- launch ----------------------------------------------------

extern "C" void kernel_launch(void* const* d_in, const int* in_sizes, int n_in,
                              void* d_out, int out_size, void* d_ws, size_t ws_size,
                              hipStream_t stream) {
    const float* query = (const float*)d_in[0];
    const float* src   = (const float*)d_in[1];
    const float* trg   = (const float*)d_in[2];
    const float* Wq    = (const float*)d_in[3];
    const float* bq    = (const float*)d_in[4];
    const float* Ws    = (const float*)d_in[5];
    const float* Wo    = (const float*)d_in[7];
    const float* bo    = (const float*)d_in[8];
    float* out = (float*)d_out;

    float* keys = (float*)d_ws;               // 1600*512 fp32 (UNBIASED)
    float* sc   = keys + 819200;              // 1024*256 fp32
    float* P    = sc   + 262144;              // 1600*512 fp32 = keys @ WoBot
    unsigned short* qh  = (unsigned short*)(P + 819200);  // 1024x512 bf16
    unsigned short* wqt = qh  + 524288;       // WqT 512x512
    unsigned short* wst = wqt + 262144;       // WsT 512x2048
    unsigned short* wot = wst + 1048576;      // WoT 512x1024

    k_prep<<<2592, 256, 0, stream>>>(Wq, Ws, Wo, wqt, wst, wot, keys);
    k_stageB<<<912, 256, 0, stream>>>(query, src, trg, wqt, wst, wot, bq, bo,
                                      qh, keys, out);
    k_stageC<<<328, 256, 0, stream>>>(qh, keys, wot + 512, sc, P);
    k_stageD<<<dim3(16, 8, 4), 256, 0, stream>>>(sc, P, out);
}